// Round 1
// baseline (623.849 us; speedup 1.0000x reference)
//
#include <hip/hip_runtime.h>
#include <math.h>

// PartitionTCA: out[i,j,k] = sum_r v0a[r,i]*v0b[r,j,k]
//                          + sum_r v1a[r,j]*v1b[r,i,k]
//                          + sum_r v2a[r,k]*v2b[r,i,j]
// D0=256 (i), D1=512 (j), D2=256 (k), ranks all 8. fp32 in/out.
// Write-bound: 134 MB out. Strategy: block tile 16x16 (i x j), K chunked by 64,
// LDS-stage the k-contiguous factors, per-thread 4i x 2j x 4k micro-tile so LDS
// read traffic ~8 floats/output (< write floor). Nontemporal stores (write-once).

typedef float f4 __attribute__((ext_vector_type(4)));

#define RNK 8
#define DD0 256
#define DD1 512
#define DD2 256
#define TI 16
#define TJ 16
#define KC 64
#define RS 68   // LDS row stride (floats): 64 + 4 pad -> 4-bank rotation per row

__global__ __launch_bounds__(256, 2)
void ptca_kernel(const float* __restrict__ v0a, const float* __restrict__ v0b,
                 const float* __restrict__ v1a, const float* __restrict__ v1b,
                 const float* __restrict__ v2a, const float* __restrict__ v2b,
                 float* __restrict__ out)
{
    __shared__ float sA0[RNK * TJ * RS];   // v0b tile: [r][jl][k]
    __shared__ float sA1[RNK * TI * RS];   // v1b tile: [r][il][k]
    __shared__ float sV2[RNK * KC];        // v2a chunk: [r][k]

    const int tid = threadIdx.x;
    const int kt = tid & 7;          // 8 k-threads, float4 each -> 32 k per pass
    const int jt = (tid >> 3) & 7;   // 8 j-threads x mj=2
    const int it = tid >> 6;         // 4 i-threads x mi=4

    const int ib = blockIdx.x * TI;
    const int jb = blockIdx.y * TJ;
    const int i0 = ib + it * 4;
    const int j0 = jb + jt * 2;

    // Per-thread invariant factors (registers, loaded once; L2/L3-served).
    float a0[RNK][4];        // v0a[r, i0+di]
    float a1[RNK][2];        // v1a[r, j0+dj]
    float s2[RNK][4][2];     // v2b[r, i0+di, j0+dj]
#pragma unroll
    for (int r = 0; r < RNK; ++r) {
#pragma unroll
        for (int di = 0; di < 4; ++di) a0[r][di] = v0a[r * DD0 + i0 + di];
#pragma unroll
        for (int dj = 0; dj < 2; ++dj) a1[r][dj] = v1a[r * DD1 + j0 + dj];
#pragma unroll
        for (int di = 0; di < 4; ++di)
#pragma unroll
            for (int dj = 0; dj < 2; ++dj)
                s2[r][di][dj] = v2b[(r * DD0 + i0 + di) * DD1 + j0 + dj];
    }

    float* outb = out + ((size_t)i0 * DD1 + j0) * DD2;

    for (int kc = 0; kc < DD2; kc += KC) {
        __syncthreads();  // protect previous chunk's LDS reads

        // Stage v0b[r][jb+jl][kc..kc+63] -> sA0 (2048 float4, 8 per thread).
        // Consecutive tids -> consecutive 16B along k: coalesced.
#pragma unroll
        for (int q = 0; q < 8; ++q) {
            const int idx = tid + q * 256;         // 0..2047
            const int kv = idx & 15;               // float4 slot along k
            const int jl = (idx >> 4) & 15;
            const int r  = idx >> 8;
            f4 v = *(const f4*)(v0b + ((r * DD1) + jb + jl) * DD2 + kc + kv * 4);
            *(f4*)(sA0 + (r * TJ + jl) * RS + kv * 4) = v;
        }
        // Stage v1b[r][ib+il][kc..kc+63] -> sA1.
#pragma unroll
        for (int q = 0; q < 8; ++q) {
            const int idx = tid + q * 256;
            const int kv = idx & 15;
            const int il = (idx >> 4) & 15;
            const int r  = idx >> 8;
            f4 v = *(const f4*)(v1b + ((r * DD0) + ib + il) * DD2 + kc + kv * 4);
            *(f4*)(sA1 + (r * TI + il) * RS + kv * 4) = v;
        }
        // Stage v2a[r][kc..kc+63] -> sV2 (128 float4).
        if (tid < 128) {
            const int kv = tid & 15;
            const int r  = tid >> 4;
            f4 v = *(const f4*)(v2a + r * DD2 + kc + kv * 4);
            *(f4*)(sV2 + r * KC + kv * 4) = v;
        }
        __syncthreads();

#pragma unroll
        for (int iter = 0; iter < 2; ++iter) {
            const int kl = iter * 32 + kt * 4;     // k offset within chunk
            f4 acc[4][2];
            const f4 zero = {0.0f, 0.0f, 0.0f, 0.0f};
#pragma unroll
            for (int di = 0; di < 4; ++di)
#pragma unroll
                for (int dj = 0; dj < 2; ++dj) acc[di][dj] = zero;

#pragma unroll
            for (int r = 0; r < RNK; ++r) {
                const f4 f2 = *(const f4*)(sV2 + r * KC + kl);
                f4 f0[2], f1[4];
#pragma unroll
                for (int dj = 0; dj < 2; ++dj)
                    f0[dj] = *(const f4*)(sA0 + (r * TJ + jt * 2 + dj) * RS + kl);
#pragma unroll
                for (int di = 0; di < 4; ++di)
                    f1[di] = *(const f4*)(sA1 + (r * TI + it * 4 + di) * RS + kl);
#pragma unroll
                for (int di = 0; di < 4; ++di)
#pragma unroll
                    for (int dj = 0; dj < 2; ++dj) {
                        const float c0 = a0[r][di];
                        const float c1 = a1[r][dj];
                        const float c2 = s2[r][di][dj];
#pragma unroll
                        for (int c = 0; c < 4; ++c)
                            acc[di][dj][c] =
                                __builtin_fmaf(c2, f2[c],
                                __builtin_fmaf(c1, f1[di][c],
                                __builtin_fmaf(c0, f0[dj][c], acc[di][dj][c])));
                    }
            }

            // 8 lanes (kt) x 16B = 128B contiguous segments; write-once -> nt.
#pragma unroll
            for (int di = 0; di < 4; ++di)
#pragma unroll
                for (int dj = 0; dj < 2; ++dj)
                    __builtin_nontemporal_store(acc[di][dj],
                        (f4*)(outb + ((size_t)(di * DD1) + dj) * DD2 + kc + kl));
        }
    }
}

extern "C" void kernel_launch(void* const* d_in, const int* in_sizes, int n_in,
                              void* d_out, int out_size, void* d_ws, size_t ws_size,
                              hipStream_t stream) {
    const float* v0a = (const float*)d_in[0];  // [8,256]
    const float* v0b = (const float*)d_in[1];  // [8,512,256]
    const float* v1a = (const float*)d_in[2];  // [8,512]
    const float* v1b = (const float*)d_in[3];  // [8,256,256]
    const float* v2a = (const float*)d_in[4];  // [8,256]
    const float* v2b = (const float*)d_in[5];  // [8,256,512]
    float* out = (float*)d_out;                // [256,512,256]

    dim3 grid(DD0 / TI, DD1 / TJ);  // (16, 32) = 512 blocks, 2 per CU
    ptca_kernel<<<grid, dim3(256), 0, stream>>>(v0a, v0b, v1a, v1b, v2a, v2b, out);
}

// Round 2
// 382.279 us; speedup vs baseline: 1.6319x; 1.6319x over previous
//
#include <hip/hip_runtime.h>

// PartitionTCA: out[i,j,k] = sum_r v0a[r,i]*v0b[r,j,k]
//                          + sum_r v1a[r,j]*v1b[r,i,k]
//                          + sum_r v2a[r,k]*v2b[r,i,j]
// D0=256 (i), D1=512 (j), D2=256 (k), rank 8, fp32.
// R2: spill fix. Register payload capped at acc(32)+s2(32); everything else LDS.
// Block tile 16i x 16j x 32k, grid (16,32,8)=4096 blocks, LDS 34KB -> 4 blocks/CU.
// One staging phase + one barrier per block. Plain f4 stores (64B line segments).
// LDS k-rotation (+4 floats per row&7) instead of padding: keeps 16B alignment.

typedef float f4 __attribute__((ext_vector_type(4)));

#define RNK 8
#define DD0 256
#define DD1 512
#define DD2 256
#define TI 16
#define TJ 16
#define KC 32

__global__ __launch_bounds__(256, 4)
void ptca_kernel(const float* __restrict__ v0a, const float* __restrict__ v0b,
                 const float* __restrict__ v1a, const float* __restrict__ v1b,
                 const float* __restrict__ v2a, const float* __restrict__ v2b,
                 float* __restrict__ out)
{
    __shared__ float sA0[RNK * TJ * 32];   // v0b tile [r][jl][k'] (k-rotated)
    __shared__ float sA1[RNK * TI * 32];   // v1b tile [r][il][k'] (k-rotated)
    __shared__ float sV2[RNK * 32];        // v2a chunk [r][k]
    __shared__ float sSa0[RNK * TI];       // v0a[r, ib+il]
    __shared__ float sSa1[RNK * TJ];       // v1a[r, jb+jl]

    const int tid = threadIdx.x;
    const int kt = tid & 3;          // k quads: lane covers k = kt*4+{0..3} and +16
    const int jt = (tid >> 2) & 7;   // j pair {jt, jt+8}
    const int it = tid >> 5;         // i pair {it, it+8}

    const int ib = blockIdx.x * TI;
    const int jb = blockIdx.y * TJ;
    const int kc = blockIdx.z * KC;

    // s2 in registers: 32 floats (wave pattern: 2 lines per load instr, L2-hot)
    float s2[RNK][2][2];
#pragma unroll
    for (int r = 0; r < RNK; ++r)
#pragma unroll
        for (int di = 0; di < 2; ++di)
#pragma unroll
            for (int dj = 0; dj < 2; ++dj)
                s2[r][di][dj] = v2b[((r * DD0) + ib + it + 8 * di) * DD1 + jb + jt + 8 * dj];

    // Stage v0b tile: 1024 f4, coalesced 128B segments per 8 lanes.
#pragma unroll
    for (int q = 0; q < 4; ++q) {
        const int idx = tid + q * 256;       // 0..1023
        const int kv = idx & 7;              // f4 slot, k = kv*4
        const int jl = (idx >> 3) & 15;
        const int r  = idx >> 7;
        f4 v = *(const f4*)(v0b + ((r * DD1) + jb + jl) * DD2 + kc + kv * 4);
        const int kp = (kv * 4 + 4 * (jl & 7)) & 31;   // rotate, 16B-aligned
        *(f4*)(sA0 + (r * TJ + jl) * 32 + kp) = v;
    }
    // Stage v1b tile.
#pragma unroll
    for (int q = 0; q < 4; ++q) {
        const int idx = tid + q * 256;
        const int kv = idx & 7;
        const int il = (idx >> 3) & 15;
        const int r  = idx >> 7;
        f4 v = *(const f4*)(v1b + ((r * DD0) + ib + il) * DD2 + kc + kv * 4);
        const int kp = (kv * 4 + 4 * (il & 7)) & 31;
        *(f4*)(sA1 + (r * TI + il) * 32 + kp) = v;
    }
    // v2a chunk (64 f4) — no rotation (rank-major rows, conflict-free reads).
    if (tid < 64) {
        const int kv = tid & 7;
        const int r  = tid >> 3;
        f4 v = *(const f4*)(v2a + r * DD2 + kc + kv * 4);
        *(f4*)(sV2 + r * 32 + kv * 4) = v;
    }
    // Factor vectors.
    if (tid < 128) {
        sSa0[tid] = v0a[(tid >> 4) * DD0 + ib + (tid & 15)];
    } else {
        const int t = tid - 128;
        sSa1[t] = v1a[(t >> 4) * DD1 + jb + (t & 15)];
    }

    __syncthreads();

    f4 acc[2][2][2];
    const f4 zero = {0.0f, 0.0f, 0.0f, 0.0f};
#pragma unroll
    for (int di = 0; di < 2; ++di)
#pragma unroll
        for (int dj = 0; dj < 2; ++dj)
#pragma unroll
            for (int p = 0; p < 2; ++p) acc[di][dj][p] = zero;

#pragma unroll
    for (int r = 0; r < RNK; ++r) {
        float a0v[2], a1v[2];
        a0v[0] = sSa0[r * TI + it];
        a0v[1] = sSa0[r * TI + it + 8];
        a1v[0] = sSa1[r * TJ + jt];
        a1v[1] = sSa1[r * TJ + jt + 8];

        f4 f2[2], f0[2][2], f1[2][2];
#pragma unroll
        for (int p = 0; p < 2; ++p) {
            const int kbase = kt * 4 + 16 * p;
            f2[p] = *(const f4*)(sV2 + r * 32 + kbase);
#pragma unroll
            for (int dj = 0; dj < 2; ++dj)
                f0[dj][p] = *(const f4*)(sA0 + (r * TJ + jt + 8 * dj) * 32 + ((kbase + 4 * jt) & 31));
#pragma unroll
            for (int di = 0; di < 2; ++di)
                f1[di][p] = *(const f4*)(sA1 + (r * TI + it + 8 * di) * 32 + ((kbase + 4 * it) & 31));
        }

#pragma unroll
        for (int di = 0; di < 2; ++di)
#pragma unroll
            for (int dj = 0; dj < 2; ++dj) {
                const float c2 = s2[r][di][dj];
#pragma unroll
                for (int p = 0; p < 2; ++p)
#pragma unroll
                    for (int c = 0; c < 4; ++c)
                        acc[di][dj][p][c] =
                            __builtin_fmaf(c2, f2[p][c],
                            __builtin_fmaf(a1v[dj], f1[di][p][c],
                            __builtin_fmaf(a0v[di], f0[dj][p][c], acc[di][dj][p][c])));
            }
    }

    // Stores: per instr, 4 kt-lanes x 16B = 64B full-line segments, x8 jt x2 it.
#pragma unroll
    for (int di = 0; di < 2; ++di)
#pragma unroll
        for (int dj = 0; dj < 2; ++dj)
#pragma unroll
            for (int p = 0; p < 2; ++p) {
                const size_t off =
                    ((size_t)(ib + it + 8 * di) * DD1 + (jb + jt + 8 * dj)) * DD2
                    + kc + kt * 4 + 16 * p;
                *(f4*)(out + off) = acc[di][dj][p];
            }
}

extern "C" void kernel_launch(void* const* d_in, const int* in_sizes, int n_in,
                              void* d_out, int out_size, void* d_ws, size_t ws_size,
                              hipStream_t stream) {
    const float* v0a = (const float*)d_in[0];  // [8,256]
    const float* v0b = (const float*)d_in[1];  // [8,512,256]
    const float* v1a = (const float*)d_in[2];  // [8,512]
    const float* v1b = (const float*)d_in[3];  // [8,256,256]
    const float* v2a = (const float*)d_in[4];  // [8,256]
    const float* v2b = (const float*)d_in[5];  // [8,256,512]
    float* out = (float*)d_out;                // [256,512,256]

    dim3 grid(DD0 / TI, DD1 / TJ, DD2 / KC);  // (16,32,8) = 4096 blocks
    ptca_kernel<<<grid, dim3(256), 0, stream>>>(v0a, v0b, v1a, v1b, v2a, v2b, out);
}

// Round 3
// 316.590 us; speedup vs baseline: 1.9705x; 1.2075x over previous
//
#include <hip/hip_runtime.h>

// PartitionTCA: out[i,j,k] = sum_r v0a[r,i]*v0b[r,j,k]
//                          + sum_r v1a[r,j]*v1b[r,i,k]
//                          + sum_r v2a[r,k]*v2b[r,i,j]
// D0=256 (i), D1=512 (j), D2=256 (k), rank 8, fp32.
// R3: wave = full k-row (64 lanes x f4 = 1KB contiguous) -> ideal LDS reads
// (m134 pattern, no extra conflicts) and full-line 1KB stores (no partial-line
// RMW). Block tile 8i x 8j x 256k; per-thread 4i x 4j f4 accumulators (64 VGPR).
// Rank split in two 4-r phases: LDS 76KB -> 2 blocks/CU. Peak live regs ~100
// < 128 cap from launch_bounds(256,2) -> no scratch spills (R2's 5.5x write
// amplification was spill traffic at VGPR=64).

typedef float f4 __attribute__((ext_vector_type(4)));

#define RNK 8
#define DD0 256
#define DD1 512
#define DD2 256
#define TI 8
#define TJ 8

__global__ __launch_bounds__(256, 2)
void ptca_kernel(const float* __restrict__ v0a, const float* __restrict__ v0b,
                 const float* __restrict__ v1a, const float* __restrict__ v1b,
                 const float* __restrict__ v2a, const float* __restrict__ v2b,
                 float* __restrict__ out)
{
    __shared__ float sA0[4 * TJ * DD2];   // v0b phase tile [rr][jl][k]  32 KB
    __shared__ float sA1[4 * TI * DD2];   // v1b phase tile [rr][il][k]  32 KB
    __shared__ float sV2[RNK * DD2];      // v2a [r][k]                   8 KB
    __shared__ float sB2[RNK * TJ * TI];  // v2b tile, transposed [r][jl][il]
    __shared__ float sa0[RNK * TI];       // v0a [r][il]
    __shared__ float sa1[RNK * TJ];       // v1a [r][jl]

    const int tid = threadIdx.x;
    const int kl  = tid & 63;           // lane = f4 slot along k (full row)
    const int wq  = tid >> 6;           // wave -> 4x4 (i,j) quad of the tile
    const int ib  = blockIdx.x * TI;
    const int jb  = blockIdx.y * TJ;
    const int iq  = (wq >> 1) * 4;      // wave's i offset in tile
    const int jq  = (wq & 1) * 4;       // wave's j offset in tile

    f4 acc[4][4];
#pragma unroll
    for (int di = 0; di < 4; ++di)
#pragma unroll
        for (int dj = 0; dj < 4; ++dj) acc[di][dj] = (f4){0.f, 0.f, 0.f, 0.f};

    // ---- one-time small stages ----
#pragma unroll
    for (int q = 0; q < 2; ++q) {                 // sV2: 512 f4 (8 KB)
        const int idx = tid + q * 256;
        const int ks = idx & 63;
        const int r  = idx >> 6;
        *(f4*)(sV2 + r * DD2 + ks * 4) = *(const f4*)(v2a + r * DD2 + ks * 4);
    }
#pragma unroll
    for (int q = 0; q < 2; ++q) {                 // sB2 transposed: 512 floats
        const int idx = tid + q * 256;
        const int jl = idx & 7;
        const int il = (idx >> 3) & 7;
        const int r  = idx >> 6;
        sB2[(r * TJ + jl) * TI + il] = v2b[(r * DD0 + ib + il) * DD1 + jb + jl];
    }
    if (tid < 64) {
        sa0[tid] = v0a[(tid >> 3) * DD0 + ib + (tid & 7)];
    } else if (tid < 128) {
        const int t = tid - 64;
        sa1[t] = v1a[(t >> 3) * DD1 + jb + (t & 7)];
    }

#pragma unroll
    for (int ph = 0; ph < 2; ++ph) {
        if (ph) __syncthreads();   // WAR: previous phase's reads done

        // ---- stage 4 ranks of v0b/v1b rows (each instr: 64x16B = 1KB coalesced)
#pragma unroll
        for (int q = 0; q < 8; ++q) {
            const int idx = tid + q * 256;        // 0..2047
            const int ks = idx & 63;
            const int jl = (idx >> 6) & 7;
            const int rr = idx >> 9;
            *(f4*)(sA0 + (rr * TJ + jl) * DD2 + ks * 4) =
                *(const f4*)(v0b + ((size_t)(4 * ph + rr) * DD1 + jb + jl) * DD2 + ks * 4);
        }
#pragma unroll
        for (int q = 0; q < 8; ++q) {
            const int idx = tid + q * 256;
            const int ks = idx & 63;
            const int il = (idx >> 6) & 7;
            const int rr = idx >> 9;
            *(f4*)(sA1 + (rr * TI + il) * DD2 + ks * 4) =
                *(const f4*)(v1b + ((size_t)(4 * ph + rr) * DD0 + ib + il) * DD2 + ks * 4);
        }
        __syncthreads();

        // ---- compute 4 ranks ----
#pragma unroll
        for (int rr = 0; rr < 4; ++rr) {
            const int r = 4 * ph + rr;
            f4 f1v[4];
#pragma unroll
            for (int di = 0; di < 4; ++di)
                f1v[di] = *(const f4*)(sA1 + (rr * TI + iq + di) * DD2 + kl * 4);
            const f4 f2v = *(const f4*)(sV2 + r * DD2 + kl * 4);
            const f4 a0v = *(const f4*)(sa0 + r * TI + iq);       // broadcast
#pragma unroll
            for (int dj = 0; dj < 4; ++dj) {
                const f4 f0v = *(const f4*)(sA0 + (rr * TJ + jq + dj) * DD2 + kl * 4);
                const f4 s2v = *(const f4*)(sB2 + (r * TJ + jq + dj) * TI + iq);
                const float a1v = sa1[r * TJ + jq + dj];
#pragma unroll
                for (int di = 0; di < 4; ++di)
#pragma unroll
                    for (int c = 0; c < 4; ++c)
                        acc[di][dj][c] =
                            __builtin_fmaf(a0v[di], f0v[c],
                            __builtin_fmaf(a1v, f1v[di][c],
                            __builtin_fmaf(s2v[di], f2v[c], acc[di][dj][c])));
            }
        }
    }

    // ---- stores: each instr writes one full 1KB contiguous k-row ----
#pragma unroll
    for (int di = 0; di < 4; ++di)
#pragma unroll
        for (int dj = 0; dj < 4; ++dj) {
            const size_t off =
                ((size_t)(ib + iq + di) * DD1 + (jb + jq + dj)) * DD2 + kl * 4;
            *(f4*)(out + off) = acc[di][dj];
        }
}

extern "C" void kernel_launch(void* const* d_in, const int* in_sizes, int n_in,
                              void* d_out, int out_size, void* d_ws, size_t ws_size,
                              hipStream_t stream) {
    const float* v0a = (const float*)d_in[0];  // [8,256]
    const float* v0b = (const float*)d_in[1];  // [8,512,256]
    const float* v1a = (const float*)d_in[2];  // [8,512]
    const float* v1b = (const float*)d_in[3];  // [8,256,256]
    const float* v2a = (const float*)d_in[4];  // [8,256]
    const float* v2b = (const float*)d_in[5];  // [8,256,512]
    float* out = (float*)d_out;                // [256,512,256]

    dim3 grid(DD0 / TI, DD1 / TJ);  // (32, 64) = 2048 blocks
    ptca_kernel<<<grid, dim3(256), 0, stream>>>(v0a, v0b, v1a, v1b, v2a, v2b, out);
}

// Round 4
// 197.911 us; speedup vs baseline: 3.1522x; 1.5997x over previous
//
#include <hip/hip_runtime.h>

// PartitionTCA: out[i,j,k] = sum_r v0a[r,i]*v0b[r,j,k]
//                          + sum_r v1a[r,j]*v1b[r,i,k]
//                          + sum_r v2a[r,k]*v2b[r,i,j]
// D0=256 (i), D1=512 (j), D2=256 (k), rank 8, fp32.
// R4: single staging phase (all 8 ranks) so acc is NEVER live across staging
// loads -> no spill possible (R3's 4.2x WRITE was scratch traffic: acc[64] live
// across phase-1 staging at the 128-VGPR cap). Nontemporal stores (write-once
// output; also defeats any L2 write-allocate on store miss). Block 8i x 8j x
// 128k, grid (32,64,2); LDS ~73KB -> 2 blocks/CU; one barrier per block.

typedef float f4 __attribute__((ext_vector_type(4)));

#define RNK 8
#define DD0 256
#define DD1 512
#define DD2 256
#define TI 8
#define TJ 8
#define KC 128
#define RS 132   // padded row stride (floats): 128+4 -> 8-bank rotation per row

__global__ __launch_bounds__(256, 2)
void ptca_kernel(const float* __restrict__ v0a, const float* __restrict__ v0b,
                 const float* __restrict__ v1a, const float* __restrict__ v1b,
                 const float* __restrict__ v2a, const float* __restrict__ v2b,
                 float* __restrict__ out)
{
    __shared__ float sA0[RNK * TJ * RS];   // v0b tile [r][jl][k]   33.8 KB
    __shared__ float sA1[RNK * TI * RS];   // v1b tile [r][il][k]   33.8 KB
    __shared__ float sV2[RNK * RS];        // v2a chunk [r][k]       4.2 KB
    __shared__ float sB2[RNK * TJ * TI];   // v2b tile [r][jl][il]   2.0 KB
    __shared__ float sa0[RNK * TI];        // v0a [r][il]
    __shared__ float sa1[RNK * TJ];        // v1a [r][jl]

    const int tid = threadIdx.x;
    const int kl  = tid & 31;          // f4 slot along k (thread covers k=kl*4..+3)
    const int jt  = (tid >> 5) & 3;    // j base: {jt*2, jt*2+1}
    const int it  = tid >> 7;          // i base: it*4 + di, di 0..3

    const int ib = blockIdx.x * TI;
    const int jb = blockIdx.y * TJ;
    const int kc = blockIdx.z * KC;

    // ---- single staging phase (no acc live yet) ----
#pragma unroll
    for (int q = 0; q < 8; ++q) {          // sA0: 2048 f4
        const int idx = tid + q * 256;
        const int kv = idx & 31;
        const int jl = (idx >> 5) & 7;
        const int r  = idx >> 8;
        *(f4*)(sA0 + (r * TJ + jl) * RS + kv * 4) =
            *(const f4*)(v0b + ((size_t)r * DD1 + jb + jl) * DD2 + kc + kv * 4);
    }
#pragma unroll
    for (int q = 0; q < 8; ++q) {          // sA1: 2048 f4
        const int idx = tid + q * 256;
        const int kv = idx & 31;
        const int il = (idx >> 5) & 7;
        const int r  = idx >> 8;
        *(f4*)(sA1 + (r * TI + il) * RS + kv * 4) =
            *(const f4*)(v1b + ((size_t)r * DD0 + ib + il) * DD2 + kc + kv * 4);
    }
    {                                      // sV2: 256 f4 (one per thread)
        const int kv = tid & 31;
        const int r  = tid >> 5;
        *(f4*)(sV2 + r * RS + kv * 4) =
            *(const f4*)(v2a + r * DD2 + kc + kv * 4);
    }
#pragma unroll
    for (int q = 0; q < 2; ++q) {          // sB2: 512 floats, [r][jl][il]
        const int idx = tid + q * 256;
        const int jl = idx & 7;
        const int il = (idx >> 3) & 7;
        const int r  = idx >> 6;
        sB2[(r * TJ + jl) * TI + il] = v2b[((size_t)r * DD0 + ib + il) * DD1 + jb + jl];
    }
    if (tid < 64) {
        sa0[tid] = v0a[(tid >> 3) * DD0 + ib + (tid & 7)];
    } else if (tid < 128) {
        const int t = tid - 64;
        sa1[t] = v1a[(t >> 3) * DD1 + jb + (t & 7)];
    }

    __syncthreads();

    // ---- compute: acc becomes live only now ----
    f4 acc[4][2];
#pragma unroll
    for (int di = 0; di < 4; ++di)
#pragma unroll
        for (int dj = 0; dj < 2; ++dj) acc[di][dj] = (f4){0.f, 0.f, 0.f, 0.f};

#pragma unroll
    for (int r = 0; r < RNK; ++r) {
        const f4 f2v = *(const f4*)(sV2 + r * RS + kl * 4);
        const f4 a0q = *(const f4*)(sa0 + r * TI + it * 4);    // a0[di]
        f4 f1v[4];
#pragma unroll
        for (int di = 0; di < 4; ++di)
            f1v[di] = *(const f4*)(sA1 + (r * TI + it * 4 + di) * RS + kl * 4);

#pragma unroll
        for (int dj = 0; dj < 2; ++dj) {
            const int j = jt * 2 + dj;
            const f4 f0v = *(const f4*)(sA0 + (r * TJ + j) * RS + kl * 4);
            const f4 s2q = *(const f4*)(sB2 + (r * TJ + j) * TI + it * 4); // s2[di]
            const float a1v = sa1[r * TJ + j];
#pragma unroll
            for (int di = 0; di < 4; ++di)
#pragma unroll
                for (int c = 0; c < 4; ++c)
                    acc[di][dj][c] =
                        __builtin_fmaf(a0q[di], f0v[c],
                        __builtin_fmaf(a1v, f1v[di][c],
                        __builtin_fmaf(s2q[di], f2v[c], acc[di][dj][c])));
        }
    }

    // ---- stores: per instr 8 x 512B contiguous segments, all full lines; nt ----
#pragma unroll
    for (int di = 0; di < 4; ++di)
#pragma unroll
        for (int dj = 0; dj < 2; ++dj) {
            const size_t off =
                ((size_t)(ib + it * 4 + di) * DD1 + (jb + jt * 2 + dj)) * DD2
                + kc + kl * 4;
            __builtin_nontemporal_store(acc[di][dj], (f4*)(out + off));
        }
}

extern "C" void kernel_launch(void* const* d_in, const int* in_sizes, int n_in,
                              void* d_out, int out_size, void* d_ws, size_t ws_size,
                              hipStream_t stream) {
    const float* v0a = (const float*)d_in[0];  // [8,256]
    const float* v0b = (const float*)d_in[1];  // [8,512,256]
    const float* v1a = (const float*)d_in[2];  // [8,512]
    const float* v1b = (const float*)d_in[3];  // [8,256,256]
    const float* v2a = (const float*)d_in[4];  // [8,256]
    const float* v2b = (const float*)d_in[5];  // [8,256,512]
    float* out = (float*)d_out;                // [256,512,256]

    dim3 grid(DD0 / TI, DD1 / TJ, DD2 / KC);  // (32,64,2) = 4096 blocks
    ptca_kernel<<<grid, dim3(256), 0, stream>>>(v0a, v0b, v1a, v1b, v2a, v2b, out);
}